// Round 6
// baseline (153.043 us; speedup 1.0000x reference)
//
#include <hip/hip_runtime.h>

// Problem constants (fixed by the reference):
//   T = B*C = 4 trees, N = 262144 = 2^18 nodes/tree, HW = 1048576 = 2^20 pixels/tree
#define NT 4
#define NN 262144
#define NMASK (NN - 1)
#define HW 1048576
#define KPRE 8192    // prefix region: solved fully in LDS by k_prefix

// Native clang vector types — __builtin_nontemporal_* rejects HIP_vector_type.
typedef int   vi4 __attribute__((ext_vector_type(4)));
typedef float vf4 __attribute__((ext_vector_type(4)));

// XCD-locality swizzle (perf heuristic): blocks dispatch round-robin across
// 8 XCDs, so tree=(b&7)>>1 keeps each XCD's random-gather working set at one
// tree (cmb 2MB + v 1MB < 4MB L2). Streams are NT so they don't evict it.
#define SWIZ(b, tree, chunk)                \
    int tree  = ((b) & 7) >> 1;             \
    int chunk = (((b) >> 3) << 1) | ((b) & 1);

// ---------------------------------------------------------------------------
// K0: prefix solve, one 1024-thread block per tree, entirely in LDS.
// Loads levels/parent/attr for nodes [0,KPRE), computes c in LDS, walks all
// KPRE chains (8/thread), writes v[0..KPRE). Zero global gathers.
// ---------------------------------------------------------------------------
__global__ __launch_bounds__(1024) void k_prefix(const float* __restrict__ attr,
                                                 const float* __restrict__ levels,
                                                 const float* __restrict__ thr,
                                                 const int* __restrict__ parent,
                                                 float* __restrict__ v) {
    __shared__ float lvcs[KPRE];             // 32KB: levels, then overwritten with c
    __shared__ unsigned short ps[KPRE];      // 16KB: parents (all < KPRE)
    int tree = blockIdx.x;
    int tbase = tree << 18;
    float t0 = thr[0];

    for (int j = threadIdx.x; j < KPRE; j += 1024) {
        lvcs[j] = levels[tbase + j];
        ps[j] = (unsigned short)(parent[tbase + j] & (KPRE - 1));
    }
    __syncthreads();

    float creg[8];
#pragma unroll
    for (int k = 0; k < 8; ++k) {
        int j = threadIdx.x + k * 1024;
        float lv = lvcs[j];
        float lp = lvcs[ps[j]];
        float z = 1000.0f * (attr[tbase + j] - t0);
        z = fminf(fmaxf(z, -12.0f), 12.0f);
        float s = 1.0f / (1.0f + __expf(-z));
        creg[k] = (j == 0) ? lv : s * (lv - lp);
    }
    __syncthreads();
#pragma unroll
    for (int k = 0; k < 8; ++k) lvcs[threadIdx.x + k * 1024] = creg[k];
    __syncthreads();

    int   cur[8];
    float acc[8];
    int alive = 0xFF;
#pragma unroll
    for (int k = 0; k < 8; ++k) { cur[k] = threadIdx.x + k * 1024; acc[k] = 0.0f; }
    // max depth of a random recursive tree @8192 ~ e*ln(8192) ~ 25; 64 = guard
    for (int it = 0; it < 64 && __any(alive); ++it) {
#pragma unroll
        for (int k = 0; k < 8; ++k) {
            if (alive & (1 << k)) {
                int c_ = cur[k];
                acc[k] += lvcs[c_];              // c[0] = levels[0] at root
                if (c_ == 0) alive &= ~(1 << k);
                else cur[k] = ps[c_];
            }
        }
    }
#pragma unroll
    for (int k = 0; k < 8; ++k)
        v[tbase + threadIdx.x + k * 1024] = acc[k];
}

// ---------------------------------------------------------------------------
// K1: build packed records cmb[i] = {parent, c} for nodes [KPRE, NN):
//   c[i] = sigmoid(clip(1000*(attr[i]-thr),-12,12)) * (levels[i]-levels[parent[i]])
// parent/attr are NT (pure streams); levels is a NORMAL read on purpose: it
// installs this tree's levels into this XCD's L2 right before the random
// levels[parent] gathers hit it. cmb writes are normal (walk re-reads them).
// ---------------------------------------------------------------------------
__global__ __launch_bounds__(256) void k_build(const float* __restrict__ attr,
                                               const float* __restrict__ levels,
                                               const float* __restrict__ thr,
                                               const int* __restrict__ parent,
                                               int2* __restrict__ cmb) {
    SWIZ(blockIdx.x, tree, chunk)            // 992 blocks, 248 chunks/tree
    int tbase = tree << 18;
    int idx4 = KPRE / 4 + chunk * 256 + threadIdx.x;   // int4-granule index
    vi4 p4 = __builtin_nontemporal_load(&((const vi4*)(parent + tbase))[idx4]);
    vf4 a4 = __builtin_nontemporal_load(&((const vf4*)(attr + tbase))[idx4]);
    vf4 l4 = ((const vf4*)(levels + tbase))[idx4];     // normal: warm L2
    float t0 = thr[0];

    int   oc[8];
#pragma unroll
    for (int e = 0; e < 4; ++e) {
        int p = p4[e] & NMASK;
        float lp = levels[tbase + p];        // tree-local random gather (L2)
        float z = 1000.0f * (a4[e] - t0);
        z = fminf(fmaxf(z, -12.0f), 12.0f);
        float s = 1.0f / (1.0f + __expf(-z));
        oc[2 * e] = p;
        oc[2 * e + 1] = __float_as_int(s * (l4[e] - lp));
    }
    vi4* dst = (vi4*)(cmb + tbase);
    dst[2 * idx4]     = (vi4){oc[0], oc[1], oc[2], oc[3]};
    dst[2 * idx4 + 1] = (vi4){oc[4], oc[5], oc[6], oc[7]};
}

// ---------------------------------------------------------------------------
// K2: main walk for nodes >= KPRE. Chain descends (avg ~2.5 steps) until it
// drops below KPRE, then folds in the precomputed prefix value (32KB/tree,
// L2-hot). 4 chains/thread for memory-level parallelism. v writes are normal
// (they are k_pix's gather target and should persist in this XCD's L2).
// ---------------------------------------------------------------------------
__global__ __launch_bounds__(256) void k_walk(const int2* __restrict__ cmb,
                                              float* __restrict__ v) {
    SWIZ(blockIdx.x, tree, chunk)            // 992 blocks, 248 chunks/tree
    int base = KPRE + chunk * 1024;
    const int2*  ct = cmb + (tree << 18);
    const float* vt = v + (tree << 18);

    int   cur[4];
    float acc[4];
    int alive = 0xF;
#pragma unroll
    for (int k = 0; k < 4; ++k) { cur[k] = base + threadIdx.x + k * 256; acc[k] = 0.0f; }

    for (int it = 0; it < 64 && __any(alive); ++it) {
#pragma unroll
        for (int k = 0; k < 4; ++k) {
            if (alive & (1 << k)) {
                int2 rec = ct[cur[k]];       // one 8B gather per step, tree-local
                acc[k] += __int_as_float(rec.y);
                int nxt = rec.x;
                if (nxt < KPRE) {            // terminate: fold in prefix value
                    acc[k] += vt[nxt];
                    alive &= ~(1 << k);
                } else {
                    cur[k] = nxt;
                }
            }
        }
    }
#pragma unroll
    for (int k = 0; k < 4; ++k)
        v[(tree << 18) + base + threadIdx.x + k * 256] = acc[k];  // coalesced
}

// ---------------------------------------------------------------------------
// K3: pixel gather y[t][p] = v[t][p2n[t][p]]. p2n read and y write are NT so
// the 8MB/XCD of streaming traffic doesn't evict the 1MB v gather target.
// ---------------------------------------------------------------------------
__global__ __launch_bounds__(256) void k_pix(const float* __restrict__ v,
                                             const int* __restrict__ p2n,
                                             float* __restrict__ y) {
    SWIZ(blockIdx.x, tree, chunk)            // 4096 blocks, 1024 chunks/tree
    int i4 = (tree << 18) + chunk * 256 + threadIdx.x;   // int4 index
    vi4 idx = __builtin_nontemporal_load(&((const vi4*)p2n)[i4]);
    const float* vt = v + (tree << 18);
    vf4 o;
    o.x = vt[idx.x & NMASK];
    o.y = vt[idx.y & NMASK];
    o.z = vt[idx.z & NMASK];
    o.w = vt[idx.w & NMASK];
    __builtin_nontemporal_store(o, &((vf4*)y)[i4]);
}

extern "C" void kernel_launch(void* const* d_in, const int* in_sizes, int n_in,
                              void* d_out, int out_size, void* d_ws, size_t ws_size,
                              hipStream_t stream) {
    // inputs: 0:x (unused), 1:attr_norm, 2:levels, 3:thr, 4:parent, 5:pixel_to_node
    const float* attr   = (const float*)d_in[1];
    const float* levels = (const float*)d_in[2];
    const float* thr    = (const float*)d_in[3];
    const int*   parent = (const int*)d_in[4];
    const int*   p2n    = (const int*)d_in[5];
    float*       y      = (float*)d_out;

    int2*  cmb = (int2*)d_ws;                                  // 8 MB
    float* v   = (float*)((char*)d_ws + (size_t)NT * NN * 8);  // 4 MB

    k_prefix<<<NT, 1024, 0, stream>>>(attr, levels, thr, parent, v);
    k_build <<<NT * (NN - KPRE) / 1024, 256, 0, stream>>>(attr, levels, thr, parent, cmb);
    k_walk  <<<NT * (NN - KPRE) / 1024, 256, 0, stream>>>(cmb, v);
    k_pix   <<<NT * HW / 1024, 256, 0, stream>>>(v, p2n, y);
}